// Round 3
// baseline (186.353 us; speedup 1.0000x reference)
//
#include <hip/hip_runtime.h>
#include <hip/hip_bf16.h>
#include <cstdint>

#define B_   2
#define T_   2048
#define C_   1024
#define NH_  16
#define HS_  64
#define WIN_ 256
#define M_   (B_*T_)   // 4096

typedef __attribute__((ext_vector_type(8))) short          short8;
typedef __attribute__((ext_vector_type(8))) unsigned short ushortx8;
typedef __attribute__((ext_vector_type(8))) __bf16         bf16x8;
typedef __attribute__((ext_vector_type(4))) float          floatx4;

__device__ __forceinline__ unsigned short f2bf(float f) {
    union { float f; uint32_t u; } v; v.f = f;
    uint32_t r = (v.u + 0x7FFFu + ((v.u >> 16) & 1u)) >> 16;
    return (unsigned short)r;
}

__device__ __forceinline__ floatx4 mfma16(short8 a, short8 b, floatx4 c) {
    return __builtin_amdgcn_mfma_f32_16x16x32_bf16(
        __builtin_bit_cast(bf16x8, a), __builtin_bit_cast(bf16x8, b), c, 0, 0, 0);
}

__device__ __forceinline__ void async16(const void* g, void* l) {
    __builtin_amdgcn_global_load_lds(
        (const __attribute__((address_space(1))) void*)g,
        (__attribute__((address_space(3))) void*)l, 16, 0, 0);
}

// ---------------------------------------------------------------------------
// Fused prep: block-range decode.
//   [0, 4096)        : x fp32 -> bf16 (1024 elems/block)
//   [4096, 4864)     : W_attn [1024][3072] -> bf16 [3072][1024]
//   [4864, 5120)     : W_proj [1024][1024] -> bf16 [1024][1024]^T
// ---------------------------------------------------------------------------
#define NB_CONV 4096
#define NB_WA   768     // 48 n-tiles x 16 k-tiles
#define NB_WP   256     // 16 x 16

__device__ void transpose_tile(const float* __restrict__ in, unsigned short* __restrict__ out,
                               int K, int N, int kt, int nt, unsigned short (*tile)[65])
{
    const int k0 = kt * 64, n0 = nt * 64;
    const int tr = threadIdx.x >> 4;          // 0..15
    const int tc = (threadIdx.x & 15) * 4;    // 0..60
    #pragma unroll
    for (int it = 0; it < 4; it++) {
        int row = tr + it * 16;   // k-local
        float4 v = *(const float4*)&in[(size_t)(k0 + row) * N + n0 + tc];
        tile[row][tc + 0] = f2bf(v.x);
        tile[row][tc + 1] = f2bf(v.y);
        tile[row][tc + 2] = f2bf(v.z);
        tile[row][tc + 3] = f2bf(v.w);
    }
    __syncthreads();
    #pragma unroll
    for (int it = 0; it < 4; it++) {
        int nrow = tr + it * 16;  // n-local
        ushort4 h;
        h.x = tile[tc + 0][nrow]; h.y = tile[tc + 1][nrow];
        h.z = tile[tc + 2][nrow]; h.w = tile[tc + 3][nrow];
        *(ushort4*)&out[(size_t)(n0 + nrow) * K + k0 + tc] = h;
    }
}

__global__ __launch_bounds__(256)
void prep_kernel(const float* __restrict__ x, const float* __restrict__ W_attn,
                 const float* __restrict__ W_proj,
                 unsigned short* __restrict__ xb, unsigned short* __restrict__ Wa_t,
                 unsigned short* __restrict__ Wp_t)
{
    __shared__ unsigned short tile[64][65];
    const int bid = blockIdx.x;
    if (bid < NB_CONV) {
        int i = (bid * 256 + threadIdx.x) * 4;
        float4 v = *(const float4*)&x[i];
        ushort4 h;
        h.x = f2bf(v.x); h.y = f2bf(v.y); h.z = f2bf(v.z); h.w = f2bf(v.w);
        *(ushort4*)&xb[i] = h;
    } else if (bid < NB_CONV + NB_WA) {
        int idx = bid - NB_CONV;
        transpose_tile(W_attn, Wa_t, C_, 3 * C_, idx / 48, idx % 48, tile);
    } else {
        int idx = bid - NB_CONV - NB_WA;
        transpose_tile(W_proj, Wp_t, C_, C_, idx / 16, idx % 16, tile);
    }
}

// ---------------------------------------------------------------------------
// V transpose: qkv V-slice [b][t][h*64+d] -> vt [b][h][d][t]   (bf16)
// ---------------------------------------------------------------------------
__global__ __launch_bounds__(256)
void vtrans_kernel(const unsigned short* __restrict__ qkv, unsigned short* __restrict__ vt)
{
    __shared__ unsigned short tile[64][65];
    const int t0 = blockIdx.x * 64;
    const int h  = blockIdx.y;
    const int b  = blockIdx.z;
    const int tr = threadIdx.x >> 4;
    const int tc = (threadIdx.x & 15) * 4;
    const size_t inbase = ((size_t)b * T_) * (3 * C_) + 2 * C_ + h * 64;
    #pragma unroll
    for (int it = 0; it < 4; it++) {
        int row = tr + it * 16;   // t-local
        ushort4 v = *(const ushort4*)&qkv[inbase + (size_t)(t0 + row) * (3 * C_) + tc];
        tile[row][tc + 0] = v.x; tile[row][tc + 1] = v.y;
        tile[row][tc + 2] = v.z; tile[row][tc + 3] = v.w;
    }
    __syncthreads();
    const size_t outbase = ((size_t)(b * NH_ + h) * 64) * T_;
    #pragma unroll
    for (int it = 0; it < 4; it++) {
        int d = tr + it * 16;
        ushort4 h4;
        h4.x = tile[tc + 0][d]; h4.y = tile[tc + 1][d];
        h4.z = tile[tc + 2][d]; h4.w = tile[tc + 3][d];
        *(ushort4*)&vt[outbase + (size_t)d * T_ + t0 + tc] = h4;
    }
}

// ---------------------------------------------------------------------------
// m97-style GEMM: C[M,N] = A[M,K] @ Bt[N,K]^T, bf16 in, fp32 acc.
// ---------------------------------------------------------------------------
template<bool OUT_BF16>
__global__ __launch_bounds__(256)
void gemm_bt(const unsigned short* __restrict__ A,
             const unsigned short* __restrict__ Bt,
             void* __restrict__ Cp, int M, int N, int K)
{
    constexpr int BK = 32;
    __shared__ unsigned short As[128 * BK];
    __shared__ unsigned short Bs[128 * BK];

    const int tid  = threadIdx.x;
    const int lane = tid & 63;
    const int wave = tid >> 6;
    const int l16  = lane & 15;
    const int quad = lane >> 4;
    const int wm   = (wave & 1) * 64;
    const int wn   = (wave >> 1) * 64;
    const int m0   = blockIdx.y * 128;
    const int n0   = blockIdx.x * 128;

    const int srow = wave * 16 + (lane >> 2);
    const int scol = (lane & 3) * 8;

    floatx4 acc[4][4];
    #pragma unroll
    for (int i = 0; i < 4; i++)
        #pragma unroll
        for (int j = 0; j < 4; j++) acc[i][j] = (floatx4){0.f, 0.f, 0.f, 0.f};

    const unsigned short* gA = &A[(size_t)(m0 + srow) * K + scol];
    const unsigned short* gB = &Bt[(size_t)(n0 + srow) * K + scol];
    unsigned short* lA = &As[wave * 16 * BK];
    unsigned short* lB = &Bs[wave * 16 * BK];

    for (int k0 = 0; k0 < K; k0 += BK) {
        async16(gA + k0,            lA);
        async16(gA + k0 + 64 * K,   lA + 64 * BK);
        async16(gB + k0,            lB);
        async16(gB + k0 + 64 * K,   lB + 64 * BK);
        __syncthreads();

        short8 af[4], bfr[4];
        #pragma unroll
        for (int i = 0; i < 4; i++)
            af[i] = *(const short8*)(&As[(wm + i * 16 + l16) * BK + quad * 8]);
        #pragma unroll
        for (int j = 0; j < 4; j++)
            bfr[j] = *(const short8*)(&Bs[(wn + j * 16 + l16) * BK + quad * 8]);
        #pragma unroll
        for (int i = 0; i < 4; i++)
            #pragma unroll
            for (int j = 0; j < 4; j++)
                acc[i][j] = mfma16(af[i], bfr[j], acc[i][j]);
        __syncthreads();
    }

    #pragma unroll
    for (int i = 0; i < 4; i++)
        #pragma unroll
        for (int j = 0; j < 4; j++)
            #pragma unroll
            for (int r = 0; r < 4; r++) {
                int row = m0 + wm + i * 16 + quad * 4 + r;
                int col = n0 + wn + j * 16 + l16;
                if (OUT_BF16)
                    ((unsigned short*)Cp)[(size_t)row * N + col] = f2bf(acc[i][j][r]);
                else
                    ((float*)Cp)[(size_t)row * N + col] = acc[i][j][r];
            }
}

// ---------------------------------------------------------------------------
// Sliding-window causal attention, flash-style. V pre-transposed in vt.
// ---------------------------------------------------------------------------
__global__ __launch_bounds__(256)
void attn_kernel(const unsigned short* __restrict__ qkv,
                 const unsigned short* __restrict__ vt,
                 unsigned short* __restrict__ y)
{
    constexpr int PD = 72;
    __shared__ unsigned short Qs[64 * PD];      // [q][d]
    __shared__ unsigned short Ks[64 * PD];      // [key][d]; reused as Ys[q][d]
    __shared__ unsigned short Vt[64 * PD];      // [d][key]
    __shared__ unsigned short Ps[4][16 * PD];   // per-wave P [q][key]

    const int tid  = threadIdx.x;
    const int lane = tid & 63;
    const int wave = tid >> 6;
    const int l16  = lane & 15;
    const int quad = lane >> 4;

    const int q0 = blockIdx.x * 64;
    const int h  = blockIdx.y;
    const int b  = blockIdx.z;
    const size_t base = (size_t)b * T_;
    const int ROW = 3 * C_;
    const int qoff = h * HS_;
    const int koff = C_ + h * HS_;
    const size_t vbase = ((size_t)(b * NH_ + h) * 64) * T_;

    #pragma unroll
    for (int it = 0; it < 4; it++) {
        int c = tid + 256 * it;
        int row = c >> 4, dc = (c & 15) << 2;
        *(ushort4*)(&Qs[row * PD + dc]) =
            *(const ushort4*)(&qkv[(base + q0 + row) * ROW + qoff + dc]);
    }

    floatx4 O[4];
    #pragma unroll
    for (int j = 0; j < 4; j++) O[j] = (floatx4){0.f, 0.f, 0.f, 0.f};
    float m_i[4], l_i[4];
    #pragma unroll
    for (int r = 0; r < 4; r++) { m_i[r] = -1e30f; l_i[r] = 0.f; }

    const int kb_lo = (q0 - WIN_) > 0 ? (q0 - WIN_) : 0;
    for (int kb = kb_lo; kb <= q0; kb += 64) {
        __syncthreads();
        // stage K tile [key][d]
        #pragma unroll
        for (int it = 0; it < 4; it++) {
            int c = tid + 256 * it;
            int row = c >> 4, dc = (c & 15) << 2;
            *(ushort4*)(&Ks[row * PD + dc]) =
                *(const ushort4*)(&qkv[(base + kb + row) * ROW + koff + dc]);
        }
        // stage V tile [d][key] from pre-transposed vt — coalesced ushort8
        #pragma unroll
        for (int it = 0; it < 2; it++) {
            int c = tid + 256 * it;
            int d = c >> 3, kc = (c & 7) * 8;
            *(ushortx8*)(&Vt[d * PD + kc]) =
                *(const ushortx8*)&vt[vbase + (size_t)d * T_ + kb + kc];
        }
        __syncthreads();

        // ---- S = Q K^T ----
        floatx4 s[4];
        #pragma unroll
        for (int nt = 0; nt < 4; nt++) s[nt] = (floatx4){0.f, 0.f, 0.f, 0.f};
        #pragma unroll
        for (int ks = 0; ks < 2; ks++) {
            short8 a = *(const short8*)(&Qs[(wave * 16 + l16) * PD + ks * 32 + quad * 8]);
            #pragma unroll
            for (int nt = 0; nt < 4; nt++) {
                short8 bb = *(const short8*)(&Ks[(nt * 16 + l16) * PD + ks * 32 + quad * 8]);
                s[nt] = mfma16(a, bb, s[nt]);
            }
        }

        const int qrb = q0 + wave * 16 + quad * 4;
        float mt[4] = {-1e30f, -1e30f, -1e30f, -1e30f};
        #pragma unroll
        for (int nt = 0; nt < 4; nt++)
            #pragma unroll
            for (int r = 0; r < 4; r++) {
                int qa = qrb + r;
                int ka = kb + nt * 16 + l16;
                float val = s[nt][r] * 0.125f;
                bool ok = (ka <= qa) && (qa - ka < WIN_);
                val = ok ? val : -1e30f;
                s[nt][r] = val;
                mt[r] = fmaxf(mt[r], val);
            }
        #pragma unroll
        for (int r = 0; r < 4; r++) {
            #pragma unroll
            for (int off = 8; off >= 1; off >>= 1)
                mt[r] = fmaxf(mt[r], __shfl_xor(mt[r], off, 64));
        }

        float alpha[4];
        #pragma unroll
        for (int r = 0; r < 4; r++) {
            float mnew = fmaxf(m_i[r], mt[r]);
            alpha[r] = __expf(m_i[r] - mnew);
            m_i[r] = mnew;
        }
        float psum[4] = {0.f, 0.f, 0.f, 0.f};
        #pragma unroll
        for (int nt = 0; nt < 4; nt++)
            #pragma unroll
            for (int r = 0; r < 4; r++) {
                float p = (s[nt][r] > -1e29f) ? __expf(s[nt][r] - m_i[r]) : 0.f;
                s[nt][r] = p;
                psum[r] += p;
            }
        #pragma unroll
        for (int r = 0; r < 4; r++) {
            #pragma unroll
            for (int off = 8; off >= 1; off >>= 1)
                psum[r] += __shfl_xor(psum[r], off, 64);
            l_i[r] = l_i[r] * alpha[r] + psum[r];
        }
        #pragma unroll
        for (int jt = 0; jt < 4; jt++)
            #pragma unroll
            for (int r = 0; r < 4; r++) O[jt][r] *= alpha[r];

        #pragma unroll
        for (int nt = 0; nt < 4; nt++)
            #pragma unroll
            for (int r = 0; r < 4; r++)
                Ps[wave][(quad * 4 + r) * PD + nt * 16 + l16] = f2bf(s[nt][r]);

        #pragma unroll
        for (int ks = 0; ks < 2; ks++) {
            short8 a = *(const short8*)(&Ps[wave][l16 * PD + ks * 32 + quad * 8]);
            #pragma unroll
            for (int jt = 0; jt < 4; jt++) {
                short8 bb = *(const short8*)(&Vt[(jt * 16 + l16) * PD + ks * 32 + quad * 8]);
                O[jt] = mfma16(a, bb, O[jt]);
            }
        }
    }

    // ---- epilogue: O -> LDS (reuse Ks) -> coalesced ushort8 global writes ----
    __syncthreads();
    #pragma unroll
    for (int jt = 0; jt < 4; jt++)
        #pragma unroll
        for (int r = 0; r < 4; r++) {
            int ql = wave * 16 + quad * 4 + r;
            Ks[ql * PD + jt * 16 + l16] = f2bf(O[jt][r] / l_i[r]);
        }
    __syncthreads();
    #pragma unroll
    for (int it = 0; it < 2; it++) {
        int c = tid + 256 * it;
        int qrow = c >> 3, dc = (c & 7) * 8;
        *(ushortx8*)&y[(base + q0 + qrow) * C_ + h * HS_ + dc] =
            *(const ushortx8*)(&Ks[qrow * PD + dc]);
    }
}

// ---------------------------------------------------------------------------
extern "C" void kernel_launch(void* const* d_in, const int* in_sizes, int n_in,
                              void* d_out, int out_size, void* d_ws, size_t ws_size,
                              hipStream_t stream)
{
    const float* x      = (const float*)d_in[0];
    const float* W_attn = (const float*)d_in[1];
    const float* W_proj = (const float*)d_in[2];
    float* out = (float*)d_out;

    unsigned short* xb   = (unsigned short*)d_ws;                 // [M][C]      8 MB
    unsigned short* Wa_t = xb   + (size_t)M_ * C_;                // [3C][C]     6 MB
    unsigned short* Wp_t = Wa_t + (size_t)3 * C_ * C_;            // [C][C]      2 MB
    unsigned short* qkv  = Wp_t + (size_t)C_ * C_;                // [M][3C]    24 MB
    unsigned short* y    = qkv  + (size_t)M_ * 3 * C_;            // [M][C]      8 MB
    unsigned short* vtg  = y    + (size_t)M_ * C_;                // [B][NH][64][T] 8 MB

    dim3 blk(256);
    prep_kernel<<<NB_CONV + NB_WA + NB_WP, blk, 0, stream>>>(x, W_attn, W_proj, xb, Wa_t, Wp_t);
    gemm_bt<true><<<dim3((3 * C_) / 128, M_ / 128), blk, 0, stream>>>(
        xb, Wa_t, qkv, M_, 3 * C_, C_);
    vtrans_kernel<<<dim3(T_ / 64, NH_, B_), blk, 0, stream>>>(qkv, vtg);
    attn_kernel<<<dim3(T_ / 64, NH_, B_), blk, 0, stream>>>(qkv, vtg, y);
    gemm_bt<false><<<dim3(C_ / 128, M_ / 128), blk, 0, stream>>>(
        y, Wp_t, out, M_, C_, C_);
}

// Round 4
// 178.500 us; speedup vs baseline: 1.0440x; 1.0440x over previous
//
#include <hip/hip_runtime.h>
#include <hip/hip_bf16.h>
#include <cstdint>

#define B_   2
#define T_   2048
#define C_   1024
#define NH_  16
#define HS_  64
#define WIN_ 256
#define M_   (B_*T_)   // 4096

typedef __attribute__((ext_vector_type(8)))  short          short8;
typedef __attribute__((ext_vector_type(8)))  unsigned short ushortx8;
typedef __attribute__((ext_vector_type(8)))  __bf16         bf16x8;
typedef __attribute__((ext_vector_type(4)))  float          floatx4;
typedef __attribute__((ext_vector_type(16))) float          floatx16;

__device__ __forceinline__ unsigned short f2bf(float f) {
    union { float f; uint32_t u; } v; v.f = f;
    uint32_t r = (v.u + 0x7FFFu + ((v.u >> 16) & 1u)) >> 16;
    return (unsigned short)r;
}

__device__ __forceinline__ floatx4 mfma16(short8 a, short8 b, floatx4 c) {
    return __builtin_amdgcn_mfma_f32_16x16x32_bf16(
        __builtin_bit_cast(bf16x8, a), __builtin_bit_cast(bf16x8, b), c, 0, 0, 0);
}
__device__ __forceinline__ floatx16 mfma32(short8 a, short8 b, floatx16 c) {
    return __builtin_amdgcn_mfma_f32_32x32x16_bf16(
        __builtin_bit_cast(bf16x8, a), __builtin_bit_cast(bf16x8, b), c, 0, 0, 0);
}

__device__ __forceinline__ void async16(const void* g, void* l) {
    __builtin_amdgcn_global_load_lds(
        (const __attribute__((address_space(1))) void*)g,
        (__attribute__((address_space(3))) void*)l, 16, 0, 0);
}

// ---------------------------------------------------------------------------
// Fused prep (x convert + both weight transposes)
// ---------------------------------------------------------------------------
#define NB_CONV 4096
#define NB_WA   768
#define NB_WP   256

__device__ void transpose_tile(const float* __restrict__ in, unsigned short* __restrict__ out,
                               int K, int N, int kt, int nt, unsigned short (*tile)[65])
{
    const int k0 = kt * 64, n0 = nt * 64;
    const int tr = threadIdx.x >> 4;
    const int tc = (threadIdx.x & 15) * 4;
    #pragma unroll
    for (int it = 0; it < 4; it++) {
        int row = tr + it * 16;
        float4 v = *(const float4*)&in[(size_t)(k0 + row) * N + n0 + tc];
        tile[row][tc + 0] = f2bf(v.x);
        tile[row][tc + 1] = f2bf(v.y);
        tile[row][tc + 2] = f2bf(v.z);
        tile[row][tc + 3] = f2bf(v.w);
    }
    __syncthreads();
    #pragma unroll
    for (int it = 0; it < 4; it++) {
        int nrow = tr + it * 16;
        ushort4 h;
        h.x = tile[tc + 0][nrow]; h.y = tile[tc + 1][nrow];
        h.z = tile[tc + 2][nrow]; h.w = tile[tc + 3][nrow];
        *(ushort4*)&out[(size_t)(n0 + nrow) * K + k0 + tc] = h;
    }
}

__global__ __launch_bounds__(256)
void prep_kernel(const float* __restrict__ x, const float* __restrict__ W_attn,
                 const float* __restrict__ W_proj,
                 unsigned short* __restrict__ xb, unsigned short* __restrict__ Wa_t,
                 unsigned short* __restrict__ Wp_t)
{
    __shared__ unsigned short tile[64][65];
    const int bid = blockIdx.x;
    if (bid < NB_CONV) {
        int i = (bid * 256 + threadIdx.x) * 4;
        float4 v = *(const float4*)&x[i];
        ushort4 h;
        h.x = f2bf(v.x); h.y = f2bf(v.y); h.z = f2bf(v.z); h.w = f2bf(v.w);
        *(ushort4*)&xb[i] = h;
    } else if (bid < NB_CONV + NB_WA) {
        int idx = bid - NB_CONV;
        transpose_tile(W_attn, Wa_t, C_, 3 * C_, idx / 48, idx % 48, tile);
    } else {
        int idx = bid - NB_CONV - NB_WA;
        transpose_tile(W_proj, Wp_t, C_, C_, idx / 16, idx % 16, tile);
    }
}

// ---------------------------------------------------------------------------
// GEMM (32x32x16 MFMA): C[M,N] = A[M,K] @ Bt[N,K]^T.
// MT=2: 128x128 block (wave: 64x64 = 2x2 32-tiles). MT=1: 64x128 block.
// VSPLIT (qkv only): cols >= 2C are V -> written transposed into vt[b][h][d][t].
// ---------------------------------------------------------------------------
template<int MT, bool OUT_BF16, bool VSPLIT>
__global__ __launch_bounds__(256)
void gemm32(const unsigned short* __restrict__ A,
            const unsigned short* __restrict__ Bt,
            void* __restrict__ Cp, unsigned short* __restrict__ vt,
            int M, int N, int K)
{
    constexpr int BK = 32;
    constexpr int BM = 64 * MT;
    __shared__ unsigned short As[BM * BK];
    __shared__ unsigned short Bs[128 * BK];

    const int tid  = threadIdx.x;
    const int lane = tid & 63;
    const int wave = tid >> 6;
    const int l32  = lane & 31;
    const int hi   = lane >> 5;           // k-octet selector
    const int wm   = (wave & 1) * 32 * MT;
    const int wn   = (wave >> 1) * 64;
    const int m0   = blockIdx.y * BM;
    const int n0   = blockIdx.x * 128;

    const int srow = wave * 16 + (lane >> 2);
    const int scol = (lane & 3) * 8;

    floatx16 acc[MT][2];
    #pragma unroll
    for (int i = 0; i < MT; i++)
        #pragma unroll
        for (int j = 0; j < 2; j++) acc[i][j] = (floatx16)(0.f);

    const unsigned short* gA = &A[(size_t)(m0 + srow) * K + scol];
    const unsigned short* gB = &Bt[(size_t)(n0 + srow) * K + scol];
    unsigned short* lA = &As[wave * 16 * BK];
    unsigned short* lB = &Bs[wave * 16 * BK];

    for (int k0 = 0; k0 < K; k0 += BK) {
        async16(gA + k0, lA);
        if (MT == 2) async16(gA + k0 + 64 * K, lA + 64 * BK);
        async16(gB + k0,          lB);
        async16(gB + k0 + 64 * K, lB + 64 * BK);
        __syncthreads();

        short8 af[MT][2], bfr[2][2];
        #pragma unroll
        for (int i = 0; i < MT; i++)
            #pragma unroll
            for (int s = 0; s < 2; s++)
                af[i][s] = *(const short8*)(&As[(wm + i * 32 + l32) * BK + s * 16 + hi * 8]);
        #pragma unroll
        for (int j = 0; j < 2; j++)
            #pragma unroll
            for (int s = 0; s < 2; s++)
                bfr[j][s] = *(const short8*)(&Bs[(wn + j * 32 + l32) * BK + s * 16 + hi * 8]);
        #pragma unroll
        for (int i = 0; i < MT; i++)
            #pragma unroll
            for (int j = 0; j < 2; j++)
                #pragma unroll
                for (int s = 0; s < 2; s++)
                    acc[i][j] = mfma32(af[i][s], bfr[j][s], acc[i][j]);
        __syncthreads();
    }

    // epilogue: C/D layout col = l32, row = (reg&3) + 8*(reg>>2) + 4*hi
    #pragma unroll
    for (int i = 0; i < MT; i++)
        #pragma unroll
        for (int j = 0; j < 2; j++) {
            const int col  = n0 + wn + j * 32 + l32;
            const int row0 = m0 + wm + i * 32 + 4 * hi;
            if (VSPLIT && col >= 2 * C_) {
                const int hd = col - 2 * C_;
                const int hh = hd >> 6, d = hd & 63;
                #pragma unroll
                for (int g = 0; g < 4; g++) {
                    int rowg = row0 + 8 * g;
                    int bb = rowg >> 11, t = rowg & (T_ - 1);
                    ushort4 h4;
                    h4.x = f2bf(acc[i][j][g * 4 + 0]);
                    h4.y = f2bf(acc[i][j][g * 4 + 1]);
                    h4.z = f2bf(acc[i][j][g * 4 + 2]);
                    h4.w = f2bf(acc[i][j][g * 4 + 3]);
                    *(ushort4*)&vt[((size_t)(bb * NH_ + hh) * 64 + d) * T_ + t] = h4;
                }
            } else {
                #pragma unroll
                for (int g = 0; g < 4; g++)
                    #pragma unroll
                    for (int rr = 0; rr < 4; rr++) {
                        int row = row0 + 8 * g + rr;
                        if (OUT_BF16)
                            ((unsigned short*)Cp)[(size_t)row * N + col] = f2bf(acc[i][j][g * 4 + rr]);
                        else
                            ((float*)Cp)[(size_t)row * N + col] = acc[i][j][g * 4 + rr];
                    }
            }
        }
}

// ---------------------------------------------------------------------------
// Sliding-window causal attention, flash-style. V pre-transposed in vt.
// ---------------------------------------------------------------------------
__global__ __launch_bounds__(256)
void attn_kernel(const unsigned short* __restrict__ qkv,
                 const unsigned short* __restrict__ vt,
                 unsigned short* __restrict__ y)
{
    constexpr int PD = 72;
    __shared__ unsigned short Qs[64 * PD];
    __shared__ unsigned short Ks[64 * PD];
    __shared__ unsigned short Vt[64 * PD];
    __shared__ unsigned short Ps[4][16 * PD];

    const int tid  = threadIdx.x;
    const int lane = tid & 63;
    const int wave = tid >> 6;
    const int l16  = lane & 15;
    const int quad = lane >> 4;

    const int q0 = blockIdx.x * 64;
    const int h  = blockIdx.y;
    const int b  = blockIdx.z;
    const size_t base = (size_t)b * T_;
    const int ROW = 3 * C_;
    const int qoff = h * HS_;
    const int koff = C_ + h * HS_;
    const size_t vbase = ((size_t)(b * NH_ + h) * 64) * T_;

    #pragma unroll
    for (int it = 0; it < 4; it++) {
        int c = tid + 256 * it;
        int row = c >> 4, dc = (c & 15) << 2;
        *(ushort4*)(&Qs[row * PD + dc]) =
            *(const ushort4*)(&qkv[(base + q0 + row) * ROW + qoff + dc]);
    }

    floatx4 O[4];
    #pragma unroll
    for (int j = 0; j < 4; j++) O[j] = (floatx4){0.f, 0.f, 0.f, 0.f};
    float m_i[4], l_i[4];
    #pragma unroll
    for (int r = 0; r < 4; r++) { m_i[r] = -1e30f; l_i[r] = 0.f; }

    const int kb_lo = (q0 - WIN_) > 0 ? (q0 - WIN_) : 0;
    for (int kb = kb_lo; kb <= q0; kb += 64) {
        __syncthreads();
        #pragma unroll
        for (int it = 0; it < 4; it++) {
            int c = tid + 256 * it;
            int row = c >> 4, dc = (c & 15) << 2;
            *(ushort4*)(&Ks[row * PD + dc]) =
                *(const ushort4*)(&qkv[(base + kb + row) * ROW + koff + dc]);
        }
        #pragma unroll
        for (int it = 0; it < 2; it++) {
            int c = tid + 256 * it;
            int d = c >> 3, kc = (c & 7) * 8;
            *(ushortx8*)(&Vt[d * PD + kc]) =
                *(const ushortx8*)&vt[vbase + (size_t)d * T_ + kb + kc];
        }
        __syncthreads();

        floatx4 s[4];
        #pragma unroll
        for (int nt = 0; nt < 4; nt++) s[nt] = (floatx4){0.f, 0.f, 0.f, 0.f};
        #pragma unroll
        for (int ks = 0; ks < 2; ks++) {
            short8 a = *(const short8*)(&Qs[(wave * 16 + l16) * PD + ks * 32 + quad * 8]);
            #pragma unroll
            for (int nt = 0; nt < 4; nt++) {
                short8 bb = *(const short8*)(&Ks[(nt * 16 + l16) * PD + ks * 32 + quad * 8]);
                s[nt] = mfma16(a, bb, s[nt]);
            }
        }

        const int qrb = q0 + wave * 16 + quad * 4;
        float mt[4] = {-1e30f, -1e30f, -1e30f, -1e30f};
        #pragma unroll
        for (int nt = 0; nt < 4; nt++)
            #pragma unroll
            for (int r = 0; r < 4; r++) {
                int qa = qrb + r;
                int ka = kb + nt * 16 + l16;
                float val = s[nt][r] * 0.125f;
                bool ok = (ka <= qa) && (qa - ka < WIN_);
                val = ok ? val : -1e30f;
                s[nt][r] = val;
                mt[r] = fmaxf(mt[r], val);
            }
        #pragma unroll
        for (int r = 0; r < 4; r++) {
            #pragma unroll
            for (int off = 8; off >= 1; off >>= 1)
                mt[r] = fmaxf(mt[r], __shfl_xor(mt[r], off, 64));
        }

        float alpha[4];
        #pragma unroll
        for (int r = 0; r < 4; r++) {
            float mnew = fmaxf(m_i[r], mt[r]);
            alpha[r] = __expf(m_i[r] - mnew);
            m_i[r] = mnew;
        }
        float psum[4] = {0.f, 0.f, 0.f, 0.f};
        #pragma unroll
        for (int nt = 0; nt < 4; nt++)
            #pragma unroll
            for (int r = 0; r < 4; r++) {
                float p = (s[nt][r] > -1e29f) ? __expf(s[nt][r] - m_i[r]) : 0.f;
                s[nt][r] = p;
                psum[r] += p;
            }
        #pragma unroll
        for (int r = 0; r < 4; r++) {
            #pragma unroll
            for (int off = 8; off >= 1; off >>= 1)
                psum[r] += __shfl_xor(psum[r], off, 64);
            l_i[r] = l_i[r] * alpha[r] + psum[r];
        }
        #pragma unroll
        for (int jt = 0; jt < 4; jt++)
            #pragma unroll
            for (int r = 0; r < 4; r++) O[jt][r] *= alpha[r];

        #pragma unroll
        for (int nt = 0; nt < 4; nt++)
            #pragma unroll
            for (int r = 0; r < 4; r++)
                Ps[wave][(quad * 4 + r) * PD + nt * 16 + l16] = f2bf(s[nt][r]);

        #pragma unroll
        for (int ks = 0; ks < 2; ks++) {
            short8 a = *(const short8*)(&Ps[wave][l16 * PD + ks * 32 + quad * 8]);
            #pragma unroll
            for (int jt = 0; jt < 4; jt++) {
                short8 bb = *(const short8*)(&Vt[(jt * 16 + l16) * PD + ks * 32 + quad * 8]);
                O[jt] = mfma16(a, bb, O[jt]);
            }
        }
    }

    __syncthreads();
    #pragma unroll
    for (int jt = 0; jt < 4; jt++)
        #pragma unroll
        for (int r = 0; r < 4; r++) {
            int ql = wave * 16 + quad * 4 + r;
            Ks[ql * PD + jt * 16 + l16] = f2bf(O[jt][r] / l_i[r]);
        }
    __syncthreads();
    #pragma unroll
    for (int it = 0; it < 2; it++) {
        int c = tid + 256 * it;
        int qrow = c >> 3, dc = (c & 7) * 8;
        *(ushortx8*)&y[(base + q0 + qrow) * C_ + h * HS_ + dc] =
            *(const ushortx8*)(&Ks[qrow * PD + dc]);
    }
}

// ---------------------------------------------------------------------------
extern "C" void kernel_launch(void* const* d_in, const int* in_sizes, int n_in,
                              void* d_out, int out_size, void* d_ws, size_t ws_size,
                              hipStream_t stream)
{
    const float* x      = (const float*)d_in[0];
    const float* W_attn = (const float*)d_in[1];
    const float* W_proj = (const float*)d_in[2];
    float* out = (float*)d_out;

    unsigned short* xb   = (unsigned short*)d_ws;                 // [M][C]      8 MB
    unsigned short* Wa_t = xb   + (size_t)M_ * C_;                // [3C][C]     6 MB
    unsigned short* Wp_t = Wa_t + (size_t)3 * C_ * C_;            // [C][C]      2 MB
    unsigned short* qkv  = Wp_t + (size_t)C_ * C_;                // [M][3C]    24 MB (Q,K only)
    unsigned short* y    = qkv  + (size_t)M_ * 3 * C_;            // [M][C]      8 MB
    unsigned short* vtg  = y    + (size_t)M_ * C_;                // [B][NH][64][T] 8 MB

    dim3 blk(256);
    prep_kernel<<<NB_CONV + NB_WA + NB_WP, blk, 0, stream>>>(x, W_attn, W_proj, xb, Wa_t, Wp_t);
    // qkv GEMM: writes Q,K into qkv rows; V transposed into vtg
    gemm32<2, true, true><<<dim3((3 * C_) / 128, M_ / 128), blk, 0, stream>>>(
        xb, Wa_t, qkv, vtg, M_, 3 * C_, C_);
    attn_kernel<<<dim3(T_ / 64, NH_, B_), blk, 0, stream>>>(qkv, vtg, y);
    // proj GEMM: 64x128 tiles -> 512 blocks (2/CU)
    gemm32<1, false, false><<<dim3(C_ / 128, M_ / 64), blk, 0, stream>>>(
        y, Wp_t, out, nullptr, M_, C_, C_);
}

// Round 5
// 172.050 us; speedup vs baseline: 1.0831x; 1.0375x over previous
//
#include <hip/hip_runtime.h>
#include <hip/hip_bf16.h>
#include <cstdint>

#define B_   2
#define T_   2048
#define C_   1024
#define NH_  16
#define HS_  64
#define WIN_ 256
#define M_   (B_*T_)   // 4096

typedef __attribute__((ext_vector_type(8)))  short          short8;
typedef __attribute__((ext_vector_type(8)))  unsigned short ushortx8;
typedef __attribute__((ext_vector_type(8)))  __bf16         bf16x8;
typedef __attribute__((ext_vector_type(4)))  float          floatx4;
typedef __attribute__((ext_vector_type(16))) float          floatx16;

__device__ __forceinline__ unsigned short f2bf(float f) {
    union { float f; uint32_t u; } v; v.f = f;
    uint32_t r = (v.u + 0x7FFFu + ((v.u >> 16) & 1u)) >> 16;
    return (unsigned short)r;
}

__device__ __forceinline__ floatx4 mfma16(short8 a, short8 b, floatx4 c) {
    return __builtin_amdgcn_mfma_f32_16x16x32_bf16(
        __builtin_bit_cast(bf16x8, a), __builtin_bit_cast(bf16x8, b), c, 0, 0, 0);
}
__device__ __forceinline__ floatx16 mfma32(short8 a, short8 b, floatx16 c) {
    return __builtin_amdgcn_mfma_f32_32x32x16_bf16(
        __builtin_bit_cast(bf16x8, a), __builtin_bit_cast(bf16x8, b), c, 0, 0, 0);
}

__device__ __forceinline__ void async16(const void* g, void* l) {
    __builtin_amdgcn_global_load_lds(
        (const __attribute__((address_space(1))) void*)g,
        (__attribute__((address_space(3))) void*)l, 16, 0, 0);
}

// ---------------------------------------------------------------------------
// Fused prep (x convert + both weight transposes)
// ---------------------------------------------------------------------------
#define NB_CONV 4096
#define NB_WA   768
#define NB_WP   256

__device__ void transpose_tile(const float* __restrict__ in, unsigned short* __restrict__ out,
                               int K, int N, int kt, int nt, unsigned short (*tile)[65])
{
    const int k0 = kt * 64, n0 = nt * 64;
    const int tr = threadIdx.x >> 4;
    const int tc = (threadIdx.x & 15) * 4;
    #pragma unroll
    for (int it = 0; it < 4; it++) {
        int row = tr + it * 16;
        float4 v = *(const float4*)&in[(size_t)(k0 + row) * N + n0 + tc];
        tile[row][tc + 0] = f2bf(v.x);
        tile[row][tc + 1] = f2bf(v.y);
        tile[row][tc + 2] = f2bf(v.z);
        tile[row][tc + 3] = f2bf(v.w);
    }
    __syncthreads();
    #pragma unroll
    for (int it = 0; it < 4; it++) {
        int nrow = tr + it * 16;
        ushort4 h;
        h.x = tile[tc + 0][nrow]; h.y = tile[tc + 1][nrow];
        h.z = tile[tc + 2][nrow]; h.w = tile[tc + 3][nrow];
        *(ushort4*)&out[(size_t)(n0 + nrow) * K + k0 + tc] = h;
    }
}

__global__ __launch_bounds__(256)
void prep_kernel(const float* __restrict__ x, const float* __restrict__ W_attn,
                 const float* __restrict__ W_proj,
                 unsigned short* __restrict__ xb, unsigned short* __restrict__ Wa_t,
                 unsigned short* __restrict__ Wp_t)
{
    __shared__ unsigned short tile[64][65];
    const int bid = blockIdx.x;
    if (bid < NB_CONV) {
        int i = (bid * 256 + threadIdx.x) * 4;
        float4 v = *(const float4*)&x[i];
        ushort4 h;
        h.x = f2bf(v.x); h.y = f2bf(v.y); h.z = f2bf(v.z); h.w = f2bf(v.w);
        *(ushort4*)&xb[i] = h;
    } else if (bid < NB_CONV + NB_WA) {
        int idx = bid - NB_CONV;
        transpose_tile(W_attn, Wa_t, C_, 3 * C_, idx / 48, idx % 48, tile);
    } else {
        int idx = bid - NB_CONV - NB_WA;
        transpose_tile(W_proj, Wp_t, C_, C_, idx / 16, idx % 16, tile);
    }
}

// ---------------------------------------------------------------------------
// GEMM (32x32x16 MFMA) with XOR-swizzled LDS to kill ds_read bank conflicts.
// LDS granule (row, p) holds global k-granule g = p ^ ((row>>1)&3).
// Swizzle applied in the global source address of global_load_lds (the LDS
// destination is fixed at lane*16), and inverted in the fragment reads.
// ---------------------------------------------------------------------------
template<int MT, bool OUT_BF16, bool VSPLIT>
__global__ __launch_bounds__(256)
void gemm32(const unsigned short* __restrict__ A,
            const unsigned short* __restrict__ Bt,
            void* __restrict__ Cp, unsigned short* __restrict__ vt,
            int M, int N, int K)
{
    constexpr int BK = 32;
    constexpr int BM = 64 * MT;
    __shared__ unsigned short As[BM * BK];
    __shared__ unsigned short Bs[128 * BK];

    const int tid  = threadIdx.x;
    const int lane = tid & 63;
    const int wave = tid >> 6;
    const int l32  = lane & 31;
    const int hi   = lane >> 5;           // k-octet selector
    const int wm   = (wave & 1) * 32 * MT;
    const int wn   = (wave >> 1) * 64;
    const int m0   = blockIdx.y * BM;
    const int n0   = blockIdx.x * 128;

    // staging: lane covers LDS-local row srow, 16-B granule (lane&3), but the
    // global source granule is swizzled: gsrc = (lane&3) ^ ((srow>>1)&3).
    // (srow+64 has the same (row>>1)&3, so both A/B halves share scol_sw.)
    const int srow    = wave * 16 + (lane >> 2);
    const int scol_sw = (((lane & 3) ^ ((srow >> 1) & 3))) * 8;

    floatx16 acc[MT][2];
    #pragma unroll
    for (int i = 0; i < MT; i++)
        #pragma unroll
        for (int j = 0; j < 2; j++) acc[i][j] = (floatx16)(0.f);

    const unsigned short* gA = &A[(size_t)(m0 + srow) * K + scol_sw];
    const unsigned short* gB = &Bt[(size_t)(n0 + srow) * K + scol_sw];
    unsigned short* lA = &As[wave * 16 * BK];
    unsigned short* lB = &Bs[wave * 16 * BK];

    for (int k0 = 0; k0 < K; k0 += BK) {
        async16(gA + k0, lA);
        if (MT == 2) async16(gA + k0 + 64 * K, lA + 64 * BK);
        async16(gB + k0,          lB);
        async16(gB + k0 + 64 * K, lB + 64 * BK);
        __syncthreads();

        short8 af[MT][2], bfr[2][2];
        #pragma unroll
        for (int i = 0; i < MT; i++)
            #pragma unroll
            for (int s = 0; s < 2; s++) {
                int r = wm + i * 32 + l32;
                int p = (s * 2 + hi) ^ ((r >> 1) & 3);
                af[i][s] = *(const short8*)(&As[r * BK + p * 8]);
            }
        #pragma unroll
        for (int j = 0; j < 2; j++)
            #pragma unroll
            for (int s = 0; s < 2; s++) {
                int r = wn + j * 32 + l32;
                int p = (s * 2 + hi) ^ ((r >> 1) & 3);
                bfr[j][s] = *(const short8*)(&Bs[r * BK + p * 8]);
            }
        #pragma unroll
        for (int i = 0; i < MT; i++)
            #pragma unroll
            for (int j = 0; j < 2; j++)
                #pragma unroll
                for (int s = 0; s < 2; s++)
                    acc[i][j] = mfma32(af[i][s], bfr[j][s], acc[i][j]);
        __syncthreads();
    }

    // epilogue: C/D layout col = l32, row = (reg&3) + 8*(reg>>2) + 4*hi
    #pragma unroll
    for (int i = 0; i < MT; i++)
        #pragma unroll
        for (int j = 0; j < 2; j++) {
            const int col  = n0 + wn + j * 32 + l32;
            const int row0 = m0 + wm + i * 32 + 4 * hi;
            if (VSPLIT && col >= 2 * C_) {
                const int hd = col - 2 * C_;
                const int hh = hd >> 6, d = hd & 63;
                #pragma unroll
                for (int g = 0; g < 4; g++) {
                    int rowg = row0 + 8 * g;
                    int bb = rowg >> 11, t = rowg & (T_ - 1);
                    ushort4 h4;
                    h4.x = f2bf(acc[i][j][g * 4 + 0]);
                    h4.y = f2bf(acc[i][j][g * 4 + 1]);
                    h4.z = f2bf(acc[i][j][g * 4 + 2]);
                    h4.w = f2bf(acc[i][j][g * 4 + 3]);
                    *(ushort4*)&vt[((size_t)(bb * NH_ + hh) * 64 + d) * T_ + t] = h4;
                }
            } else {
                #pragma unroll
                for (int g = 0; g < 4; g++)
                    #pragma unroll
                    for (int rr = 0; rr < 4; rr++) {
                        int row = row0 + 8 * g + rr;
                        if (OUT_BF16)
                            ((unsigned short*)Cp)[(size_t)row * N + col] = f2bf(acc[i][j][g * 4 + rr]);
                        else
                            ((float*)Cp)[(size_t)row * N + col] = acc[i][j][g * 4 + rr];
                    }
            }
        }
}

// ---------------------------------------------------------------------------
// Sliding-window causal attention, flash-style. V pre-transposed in vt.
// ---------------------------------------------------------------------------
__global__ __launch_bounds__(256)
void attn_kernel(const unsigned short* __restrict__ qkv,
                 const unsigned short* __restrict__ vt,
                 unsigned short* __restrict__ y)
{
    constexpr int PD = 72;
    __shared__ unsigned short Qs[64 * PD];
    __shared__ unsigned short Ks[64 * PD];
    __shared__ unsigned short Vt[64 * PD];
    __shared__ unsigned short Ps[4][16 * PD];

    const int tid  = threadIdx.x;
    const int lane = tid & 63;
    const int wave = tid >> 6;
    const int l16  = lane & 15;
    const int quad = lane >> 4;

    const int q0 = blockIdx.x * 64;
    const int h  = blockIdx.y;
    const int b  = blockIdx.z;
    const size_t base = (size_t)b * T_;
    const int ROW = 3 * C_;
    const int qoff = h * HS_;
    const int koff = C_ + h * HS_;
    const size_t vbase = ((size_t)(b * NH_ + h) * 64) * T_;

    #pragma unroll
    for (int it = 0; it < 4; it++) {
        int c = tid + 256 * it;
        int row = c >> 4, dc = (c & 15) << 2;
        *(ushort4*)(&Qs[row * PD + dc]) =
            *(const ushort4*)(&qkv[(base + q0 + row) * ROW + qoff + dc]);
    }

    floatx4 O[4];
    #pragma unroll
    for (int j = 0; j < 4; j++) O[j] = (floatx4){0.f, 0.f, 0.f, 0.f};
    float m_i[4], l_i[4];
    #pragma unroll
    for (int r = 0; r < 4; r++) { m_i[r] = -1e30f; l_i[r] = 0.f; }

    const int kb_lo = (q0 - WIN_) > 0 ? (q0 - WIN_) : 0;
    for (int kb = kb_lo; kb <= q0; kb += 64) {
        __syncthreads();
        #pragma unroll
        for (int it = 0; it < 4; it++) {
            int c = tid + 256 * it;
            int row = c >> 4, dc = (c & 15) << 2;
            *(ushort4*)(&Ks[row * PD + dc]) =
                *(const ushort4*)(&qkv[(base + kb + row) * ROW + koff + dc]);
        }
        #pragma unroll
        for (int it = 0; it < 2; it++) {
            int c = tid + 256 * it;
            int d = c >> 3, kc = (c & 7) * 8;
            *(ushortx8*)(&Vt[d * PD + kc]) =
                *(const ushortx8*)&vt[vbase + (size_t)d * T_ + kb + kc];
        }
        __syncthreads();

        floatx4 s[4];
        #pragma unroll
        for (int nt = 0; nt < 4; nt++) s[nt] = (floatx4){0.f, 0.f, 0.f, 0.f};
        #pragma unroll
        for (int ks = 0; ks < 2; ks++) {
            short8 a = *(const short8*)(&Qs[(wave * 16 + l16) * PD + ks * 32 + quad * 8]);
            #pragma unroll
            for (int nt = 0; nt < 4; nt++) {
                short8 bb = *(const short8*)(&Ks[(nt * 16 + l16) * PD + ks * 32 + quad * 8]);
                s[nt] = mfma16(a, bb, s[nt]);
            }
        }

        const int qrb = q0 + wave * 16 + quad * 4;
        float mt[4] = {-1e30f, -1e30f, -1e30f, -1e30f};
        #pragma unroll
        for (int nt = 0; nt < 4; nt++)
            #pragma unroll
            for (int r = 0; r < 4; r++) {
                int qa = qrb + r;
                int ka = kb + nt * 16 + l16;
                float val = s[nt][r] * 0.125f;
                bool ok = (ka <= qa) && (qa - ka < WIN_);
                val = ok ? val : -1e30f;
                s[nt][r] = val;
                mt[r] = fmaxf(mt[r], val);
            }
        #pragma unroll
        for (int r = 0; r < 4; r++) {
            #pragma unroll
            for (int off = 8; off >= 1; off >>= 1)
                mt[r] = fmaxf(mt[r], __shfl_xor(mt[r], off, 64));
        }

        float alpha[4];
        #pragma unroll
        for (int r = 0; r < 4; r++) {
            float mnew = fmaxf(m_i[r], mt[r]);
            alpha[r] = __expf(m_i[r] - mnew);
            m_i[r] = mnew;
        }
        float psum[4] = {0.f, 0.f, 0.f, 0.f};
        #pragma unroll
        for (int nt = 0; nt < 4; nt++)
            #pragma unroll
            for (int r = 0; r < 4; r++) {
                float p = (s[nt][r] > -1e29f) ? __expf(s[nt][r] - m_i[r]) : 0.f;
                s[nt][r] = p;
                psum[r] += p;
            }
        #pragma unroll
        for (int r = 0; r < 4; r++) {
            #pragma unroll
            for (int off = 8; off >= 1; off >>= 1)
                psum[r] += __shfl_xor(psum[r], off, 64);
            l_i[r] = l_i[r] * alpha[r] + psum[r];
        }
        #pragma unroll
        for (int jt = 0; jt < 4; jt++)
            #pragma unroll
            for (int r = 0; r < 4; r++) O[jt][r] *= alpha[r];

        #pragma unroll
        for (int nt = 0; nt < 4; nt++)
            #pragma unroll
            for (int r = 0; r < 4; r++)
                Ps[wave][(quad * 4 + r) * PD + nt * 16 + l16] = f2bf(s[nt][r]);

        #pragma unroll
        for (int ks = 0; ks < 2; ks++) {
            short8 a = *(const short8*)(&Ps[wave][l16 * PD + ks * 32 + quad * 8]);
            #pragma unroll
            for (int jt = 0; jt < 4; jt++) {
                short8 bb = *(const short8*)(&Vt[(jt * 16 + l16) * PD + ks * 32 + quad * 8]);
                O[jt] = mfma16(a, bb, O[jt]);
            }
        }
    }

    __syncthreads();
    #pragma unroll
    for (int jt = 0; jt < 4; jt++)
        #pragma unroll
        for (int r = 0; r < 4; r++) {
            int ql = wave * 16 + quad * 4 + r;
            Ks[ql * PD + jt * 16 + l16] = f2bf(O[jt][r] / l_i[r]);
        }
    __syncthreads();
    #pragma unroll
    for (int it = 0; it < 2; it++) {
        int c = tid + 256 * it;
        int qrow = c >> 3, dc = (c & 7) * 8;
        *(ushortx8*)&y[(base + q0 + qrow) * C_ + h * HS_ + dc] =
            *(const ushortx8*)(&Ks[qrow * PD + dc]);
    }
}

// ---------------------------------------------------------------------------
extern "C" void kernel_launch(void* const* d_in, const int* in_sizes, int n_in,
                              void* d_out, int out_size, void* d_ws, size_t ws_size,
                              hipStream_t stream)
{
    const float* x      = (const float*)d_in[0];
    const float* W_attn = (const float*)d_in[1];
    const float* W_proj = (const float*)d_in[2];
    float* out = (float*)d_out;

    unsigned short* xb   = (unsigned short*)d_ws;                 // [M][C]      8 MB
    unsigned short* Wa_t = xb   + (size_t)M_ * C_;                // [3C][C]     6 MB
    unsigned short* Wp_t = Wa_t + (size_t)3 * C_ * C_;            // [C][C]      2 MB
    unsigned short* qkv  = Wp_t + (size_t)C_ * C_;                // [M][3C]    24 MB (Q,K only)
    unsigned short* y    = qkv  + (size_t)M_ * 3 * C_;            // [M][C]      8 MB
    unsigned short* vtg  = y    + (size_t)M_ * C_;                // [B][NH][64][T] 8 MB

    dim3 blk(256);
    prep_kernel<<<NB_CONV + NB_WA + NB_WP, blk, 0, stream>>>(x, W_attn, W_proj, xb, Wa_t, Wp_t);
    gemm32<2, true, true><<<dim3((3 * C_) / 128, M_ / 128), blk, 0, stream>>>(
        xb, Wa_t, qkv, vtg, M_, 3 * C_, C_);
    attn_kernel<<<dim3(T_ / 64, NH_, B_), blk, 0, stream>>>(qkv, vtg, y);
    gemm32<1, false, false><<<dim3(C_ / 128, M_ / 64), blk, 0, stream>>>(
        y, Wp_t, out, nullptr, M_, C_, C_);
}

// Round 6
// 167.769 us; speedup vs baseline: 1.1108x; 1.0255x over previous
//
#include <hip/hip_runtime.h>
#include <hip/hip_bf16.h>
#include <cstdint>

#define B_   2
#define T_   2048
#define C_   1024
#define NH_  16
#define HS_  64
#define WIN_ 256
#define M_   (B_*T_)   // 4096

typedef __attribute__((ext_vector_type(8)))  short          short8;
typedef __attribute__((ext_vector_type(8)))  unsigned short ushortx8;
typedef __attribute__((ext_vector_type(8)))  __bf16         bf16x8;
typedef __attribute__((ext_vector_type(4)))  float          floatx4;
typedef __attribute__((ext_vector_type(16))) float          floatx16;

__device__ __forceinline__ unsigned short f2bf(float f) {
    union { float f; uint32_t u; } v; v.f = f;
    uint32_t r = (v.u + 0x7FFFu + ((v.u >> 16) & 1u)) >> 16;
    return (unsigned short)r;
}

__device__ __forceinline__ floatx4 mfma16(short8 a, short8 b, floatx4 c) {
    return __builtin_amdgcn_mfma_f32_16x16x32_bf16(
        __builtin_bit_cast(bf16x8, a), __builtin_bit_cast(bf16x8, b), c, 0, 0, 0);
}
__device__ __forceinline__ floatx16 mfma32(short8 a, short8 b, floatx16 c) {
    return __builtin_amdgcn_mfma_f32_32x32x16_bf16(
        __builtin_bit_cast(bf16x8, a), __builtin_bit_cast(bf16x8, b), c, 0, 0, 0);
}

__device__ __forceinline__ void async16(const void* g, void* l) {
    __builtin_amdgcn_global_load_lds(
        (const __attribute__((address_space(1))) void*)g,
        (__attribute__((address_space(3))) void*)l, 16, 0, 0);
}

// ---------------------------------------------------------------------------
// Fused prep (x convert + both weight transposes)
// ---------------------------------------------------------------------------
#define NB_CONV 4096
#define NB_WA   768
#define NB_WP   256

__device__ void transpose_tile(const float* __restrict__ in, unsigned short* __restrict__ out,
                               int K, int N, int kt, int nt, unsigned short (*tile)[65])
{
    const int k0 = kt * 64, n0 = nt * 64;
    const int tr = threadIdx.x >> 4;
    const int tc = (threadIdx.x & 15) * 4;
    #pragma unroll
    for (int it = 0; it < 4; it++) {
        int row = tr + it * 16;
        float4 v = *(const float4*)&in[(size_t)(k0 + row) * N + n0 + tc];
        tile[row][tc + 0] = f2bf(v.x);
        tile[row][tc + 1] = f2bf(v.y);
        tile[row][tc + 2] = f2bf(v.z);
        tile[row][tc + 3] = f2bf(v.w);
    }
    __syncthreads();
    #pragma unroll
    for (int it = 0; it < 4; it++) {
        int nrow = tr + it * 16;
        ushort4 h;
        h.x = tile[tc + 0][nrow]; h.y = tile[tc + 1][nrow];
        h.z = tile[tc + 2][nrow]; h.w = tile[tc + 3][nrow];
        *(ushort4*)&out[(size_t)(n0 + nrow) * K + k0 + tc] = h;
    }
}

__global__ __launch_bounds__(256)
void prep_kernel(const float* __restrict__ x, const float* __restrict__ W_attn,
                 const float* __restrict__ W_proj,
                 unsigned short* __restrict__ xb, unsigned short* __restrict__ Wa_t,
                 unsigned short* __restrict__ Wp_t)
{
    __shared__ unsigned short tile[64][65];
    const int bid = blockIdx.x;
    if (bid < NB_CONV) {
        int i = (bid * 256 + threadIdx.x) * 4;
        float4 v = *(const float4*)&x[i];
        ushort4 h;
        h.x = f2bf(v.x); h.y = f2bf(v.y); h.z = f2bf(v.z); h.w = f2bf(v.w);
        *(ushort4*)&xb[i] = h;
    } else if (bid < NB_CONV + NB_WA) {
        int idx = bid - NB_CONV;
        transpose_tile(W_attn, Wa_t, C_, 3 * C_, idx / 48, idx % 48, tile);
    } else {
        int idx = bid - NB_CONV - NB_WA;
        transpose_tile(W_proj, Wp_t, C_, C_, idx / 16, idx % 16, tile);
    }
}

// ---------------------------------------------------------------------------
// GEMM, 32x32x16 MFMA, BK=64 (16 K-iterations for K=1024 -> half the barriers).
// XOR swizzle: row stride = 128 B (8 x 16-B granules); LDS granule (r,p) holds
// global k-granule g = p ^ (r & 7). Staging: lane = 8*ri + p covers row r0+ri,
// global granule p ^ ri -> contiguous 128 B per 8-lane row group (coalesced),
// LDS dst = wave-uniform base + lane*16. Fragment reads spread over all 8
// bank-groups (aggregate conflict-free).
// ---------------------------------------------------------------------------
template<int MT, bool OUT_BF16, bool VSPLIT>
__global__ __launch_bounds__(256)
void gemm32(const unsigned short* __restrict__ A,
            const unsigned short* __restrict__ Bt,
            void* __restrict__ Cp, unsigned short* __restrict__ vt,
            int M, int N, int K)
{
    constexpr int BK = 64;
    constexpr int BM = 64 * MT;
    __shared__ unsigned short As[BM * BK];
    __shared__ unsigned short Bs[128 * BK];

    const int tid  = threadIdx.x;
    const int lane = tid & 63;
    const int wave = tid >> 6;
    const int l32  = lane & 31;
    const int hi   = lane >> 5;           // k-octet parity
    const int px   = l32 & 7;             // fragment swizzle key (= r & 7)
    const int wm   = (wave & 1) * 32 * MT;
    const int wn   = (wave >> 1) * 64;
    const int m0   = blockIdx.y * BM;
    const int n0   = blockIdx.x * 128;

    // staging decomposition: lane = 8*ri + p
    const int ri = lane >> 3;             // row within 8-row group
    const int pg = lane & 7;              // physical LDS granule
    const int gg = pg ^ ri;               // global k-granule (swizzle)

    floatx16 acc[MT][2];
    #pragma unroll
    for (int i = 0; i < MT; i++)
        #pragma unroll
        for (int j = 0; j < 2; j++) acc[i][j] = (floatx16)(0.f);

    const unsigned short* gA = &A[(size_t)(m0 + wave * 8 + ri) * K + gg * 8];
    const unsigned short* gB = &Bt[(size_t)(n0 + wave * 8 + ri) * K + gg * 8];
    unsigned short* lA = &As[(wave * 8) * BK];
    unsigned short* lB = &Bs[(wave * 8) * BK];

    for (int k0 = 0; k0 < K; k0 += BK) {
        #pragma unroll
        for (int s = 0; s < 2 * MT; s++)
            async16(gA + k0 + (size_t)s * 32 * K, lA + s * 32 * BK);
        #pragma unroll
        for (int s = 0; s < 4; s++)
            async16(gB + k0 + (size_t)s * 32 * K, lB + s * 32 * BK);
        __syncthreads();

        #pragma unroll
        for (int ks = 0; ks < 4; ks++) {
            short8 af[MT], bfr[2];
            #pragma unroll
            for (int i = 0; i < MT; i++) {
                int r = wm + i * 32 + l32;
                int p = (ks * 2 + hi) ^ px;
                af[i] = *(const short8*)(&As[r * BK + p * 8]);
            }
            #pragma unroll
            for (int j = 0; j < 2; j++) {
                int r = wn + j * 32 + l32;
                int p = (ks * 2 + hi) ^ px;
                bfr[j] = *(const short8*)(&Bs[r * BK + p * 8]);
            }
            #pragma unroll
            for (int i = 0; i < MT; i++)
                #pragma unroll
                for (int j = 0; j < 2; j++)
                    acc[i][j] = mfma32(af[i], bfr[j], acc[i][j]);
        }
        __syncthreads();
    }

    // epilogue: C/D layout col = l32, row = (reg&3) + 8*(reg>>2) + 4*hi
    #pragma unroll
    for (int i = 0; i < MT; i++)
        #pragma unroll
        for (int j = 0; j < 2; j++) {
            const int col  = n0 + wn + j * 32 + l32;
            const int row0 = m0 + wm + i * 32 + 4 * hi;
            if (VSPLIT && col >= 2 * C_) {
                const int hd = col - 2 * C_;
                const int hh = hd >> 6, d = hd & 63;
                #pragma unroll
                for (int g = 0; g < 4; g++) {
                    int rowg = row0 + 8 * g;
                    int bb = rowg >> 11, t = rowg & (T_ - 1);
                    ushort4 h4;
                    h4.x = f2bf(acc[i][j][g * 4 + 0]);
                    h4.y = f2bf(acc[i][j][g * 4 + 1]);
                    h4.z = f2bf(acc[i][j][g * 4 + 2]);
                    h4.w = f2bf(acc[i][j][g * 4 + 3]);
                    *(ushort4*)&vt[((size_t)(bb * NH_ + hh) * 64 + d) * T_ + t] = h4;
                }
            } else {
                #pragma unroll
                for (int g = 0; g < 4; g++)
                    #pragma unroll
                    for (int rr = 0; rr < 4; rr++) {
                        int row = row0 + 8 * g + rr;
                        if (OUT_BF16)
                            ((unsigned short*)Cp)[(size_t)row * N + col] = f2bf(acc[i][j][g * 4 + rr]);
                        else
                            ((float*)Cp)[(size_t)row * N + col] = acc[i][j][g * 4 + rr];
                    }
            }
        }
}

// ---------------------------------------------------------------------------
// Sliding-window causal attention, flash-style. V pre-transposed in vt.
// ---------------------------------------------------------------------------
__global__ __launch_bounds__(256)
void attn_kernel(const unsigned short* __restrict__ qkv,
                 const unsigned short* __restrict__ vt,
                 unsigned short* __restrict__ y)
{
    constexpr int PD = 72;
    __shared__ unsigned short Qs[64 * PD];
    __shared__ unsigned short Ks[64 * PD];
    __shared__ unsigned short Vt[64 * PD];
    __shared__ unsigned short Ps[4][16 * PD];

    const int tid  = threadIdx.x;
    const int lane = tid & 63;
    const int wave = tid >> 6;
    const int l16  = lane & 15;
    const int quad = lane >> 4;

    const int q0 = blockIdx.x * 64;
    const int h  = blockIdx.y;
    const int b  = blockIdx.z;
    const size_t base = (size_t)b * T_;
    const int ROW = 3 * C_;
    const int qoff = h * HS_;
    const int koff = C_ + h * HS_;
    const size_t vbase = ((size_t)(b * NH_ + h) * 64) * T_;

    #pragma unroll
    for (int it = 0; it < 4; it++) {
        int c = tid + 256 * it;
        int row = c >> 4, dc = (c & 15) << 2;
        *(ushort4*)(&Qs[row * PD + dc]) =
            *(const ushort4*)(&qkv[(base + q0 + row) * ROW + qoff + dc]);
    }

    floatx4 O[4];
    #pragma unroll
    for (int j = 0; j < 4; j++) O[j] = (floatx4){0.f, 0.f, 0.f, 0.f};
    float m_i[4], l_i[4];
    #pragma unroll
    for (int r = 0; r < 4; r++) { m_i[r] = -1e30f; l_i[r] = 0.f; }

    const int kb_lo = (q0 - WIN_) > 0 ? (q0 - WIN_) : 0;
    for (int kb = kb_lo; kb <= q0; kb += 64) {
        __syncthreads();
        #pragma unroll
        for (int it = 0; it < 4; it++) {
            int c = tid + 256 * it;
            int row = c >> 4, dc = (c & 15) << 2;
            *(ushort4*)(&Ks[row * PD + dc]) =
                *(const ushort4*)(&qkv[(base + kb + row) * ROW + koff + dc]);
        }
        #pragma unroll
        for (int it = 0; it < 2; it++) {
            int c = tid + 256 * it;
            int d = c >> 3, kc = (c & 7) * 8;
            *(ushortx8*)(&Vt[d * PD + kc]) =
                *(const ushortx8*)&vt[vbase + (size_t)d * T_ + kb + kc];
        }
        __syncthreads();

        floatx4 s[4];
        #pragma unroll
        for (int nt = 0; nt < 4; nt++) s[nt] = (floatx4){0.f, 0.f, 0.f, 0.f};
        #pragma unroll
        for (int ks = 0; ks < 2; ks++) {
            short8 a = *(const short8*)(&Qs[(wave * 16 + l16) * PD + ks * 32 + quad * 8]);
            #pragma unroll
            for (int nt = 0; nt < 4; nt++) {
                short8 bb = *(const short8*)(&Ks[(nt * 16 + l16) * PD + ks * 32 + quad * 8]);
                s[nt] = mfma16(a, bb, s[nt]);
            }
        }

        const int qrb = q0 + wave * 16 + quad * 4;
        float mt[4] = {-1e30f, -1e30f, -1e30f, -1e30f};
        #pragma unroll
        for (int nt = 0; nt < 4; nt++)
            #pragma unroll
            for (int r = 0; r < 4; r++) {
                int qa = qrb + r;
                int ka = kb + nt * 16 + l16;
                float val = s[nt][r] * 0.125f;
                bool ok = (ka <= qa) && (qa - ka < WIN_);
                val = ok ? val : -1e30f;
                s[nt][r] = val;
                mt[r] = fmaxf(mt[r], val);
            }
        #pragma unroll
        for (int r = 0; r < 4; r++) {
            #pragma unroll
            for (int off = 8; off >= 1; off >>= 1)
                mt[r] = fmaxf(mt[r], __shfl_xor(mt[r], off, 64));
        }

        float alpha[4];
        #pragma unroll
        for (int r = 0; r < 4; r++) {
            float mnew = fmaxf(m_i[r], mt[r]);
            alpha[r] = __expf(m_i[r] - mnew);
            m_i[r] = mnew;
        }
        float psum[4] = {0.f, 0.f, 0.f, 0.f};
        #pragma unroll
        for (int nt = 0; nt < 4; nt++)
            #pragma unroll
            for (int r = 0; r < 4; r++) {
                float p = (s[nt][r] > -1e29f) ? __expf(s[nt][r] - m_i[r]) : 0.f;
                s[nt][r] = p;
                psum[r] += p;
            }
        #pragma unroll
        for (int r = 0; r < 4; r++) {
            #pragma unroll
            for (int off = 8; off >= 1; off >>= 1)
                psum[r] += __shfl_xor(psum[r], off, 64);
            l_i[r] = l_i[r] * alpha[r] + psum[r];
        }
        #pragma unroll
        for (int jt = 0; jt < 4; jt++)
            #pragma unroll
            for (int r = 0; r < 4; r++) O[jt][r] *= alpha[r];

        #pragma unroll
        for (int nt = 0; nt < 4; nt++)
            #pragma unroll
            for (int r = 0; r < 4; r++)
                Ps[wave][(quad * 4 + r) * PD + nt * 16 + l16] = f2bf(s[nt][r]);

        #pragma unroll
        for (int ks = 0; ks < 2; ks++) {
            short8 a = *(const short8*)(&Ps[wave][l16 * PD + ks * 32 + quad * 8]);
            #pragma unroll
            for (int jt = 0; jt < 4; jt++) {
                short8 bb = *(const short8*)(&Vt[(jt * 16 + l16) * PD + ks * 32 + quad * 8]);
                O[jt] = mfma16(a, bb, O[jt]);
            }
        }
    }

    __syncthreads();
    #pragma unroll
    for (int jt = 0; jt < 4; jt++)
        #pragma unroll
        for (int r = 0; r < 4; r++) {
            int ql = wave * 16 + quad * 4 + r;
            Ks[ql * PD + jt * 16 + l16] = f2bf(O[jt][r] / l_i[r]);
        }
    __syncthreads();
    #pragma unroll
    for (int it = 0; it < 2; it++) {
        int c = tid + 256 * it;
        int qrow = c >> 3, dc = (c & 7) * 8;
        *(ushortx8*)&y[(base + q0 + qrow) * C_ + h * HS_ + dc] =
            *(const ushortx8*)(&Ks[qrow * PD + dc]);
    }
}

// ---------------------------------------------------------------------------
extern "C" void kernel_launch(void* const* d_in, const int* in_sizes, int n_in,
                              void* d_out, int out_size, void* d_ws, size_t ws_size,
                              hipStream_t stream)
{
    const float* x      = (const float*)d_in[0];
    const float* W_attn = (const float*)d_in[1];
    const float* W_proj = (const float*)d_in[2];
    float* out = (float*)d_out;

    unsigned short* xb   = (unsigned short*)d_ws;                 // [M][C]      8 MB
    unsigned short* Wa_t = xb   + (size_t)M_ * C_;                // [3C][C]     6 MB
    unsigned short* Wp_t = Wa_t + (size_t)3 * C_ * C_;            // [C][C]      2 MB
    unsigned short* qkv  = Wp_t + (size_t)C_ * C_;                // [M][3C]    24 MB (Q,K only)
    unsigned short* y    = qkv  + (size_t)M_ * 3 * C_;            // [M][C]      8 MB
    unsigned short* vtg  = y    + (size_t)M_ * C_;                // [B][NH][64][T] 8 MB

    dim3 blk(256);
    prep_kernel<<<NB_CONV + NB_WA + NB_WP, blk, 0, stream>>>(x, W_attn, W_proj, xb, Wa_t, Wp_t);
    gemm32<2, true, true><<<dim3((3 * C_) / 128, M_ / 128), blk, 0, stream>>>(
        xb, Wa_t, qkv, vtg, M_, 3 * C_, C_);
    attn_kernel<<<dim3(T_ / 64, NH_, B_), blk, 0, stream>>>(qkv, vtg, y);
    gemm32<1, false, false><<<dim3(C_ / 128, M_ / 64), blk, 0, stream>>>(
        y, Wp_t, out, nullptr, M_, C_, C_);
}